// Round 1
// baseline (295.477 us; speedup 1.0000x reference)
//
#include <hip/hip_runtime.h>
#include <hip/hip_bf16.h>

#define NN 4096
#define HID 2048
#define BATCH 64
#define NSEG 32
#define ISEG 128          // 4096/32
#define LOG2E 1.4426950408889634f

__device__ __forceinline__ float sig_from_n(float n) {
    // n = -(c+a)*log2e  ->  sigmoid = 1/(1+2^n)
    return __builtin_amdgcn_rcpf(1.0f + __builtin_amdgcn_exp2f(n));
}

// ---------------- K0: pack x bits ----------------
__global__ __launch_bounds__(256) void k_pack(const float* __restrict__ x,
                                              unsigned long long* __restrict__ xbits) {
    int gw = blockIdx.x * 4 + (threadIdx.x >> 6);   // global wave id, 0..4095
    int lane = threadIdx.x & 63;
    int b = gw >> 6, w = gw & 63;
    float v = x[(size_t)b * NN + w * 64 + lane];
    unsigned long long m = __ballot(v > 0.5f);
    if (lane == 0) xbits[b * 64 + w] = m;
}

// ---------------- K1: per-segment sums C[seg][b][h] ----------------
__global__ __launch_bounds__(256) void k_partial(const float* __restrict__ W,
                                                 const unsigned* __restrict__ xb32,
                                                 float* __restrict__ C) {
    __shared__ float lw[32 * 260];
    const int tid = threadIdx.x;
    const int lane = tid & 63;
    const int wv = tid >> 6;
    const int hb = blockIdx.x * 256;
    const int ib = blockIdx.y * ISEG;
    const int bb = wv * 16;

    float4 acc[16];
    #pragma unroll
    for (int k = 0; k < 16; ++k) acc[k] = make_float4(0.f, 0.f, 0.f, 0.f);

    for (int t = 0; t < 4; ++t) {
        const int i0 = ib + t * 32;
        __syncthreads();
        #pragma unroll
        for (int rep = 0; rep < 8; ++rep) {
            int idx = rep * 256 + tid;
            int row = idx >> 3, q = idx & 7;
            float4 w4 = *(const float4*)&W[(size_t)(hb + row) * NN + i0 + q * 4];
            int il = q * 4;
            lw[(il + 0) * 260 + row] = w4.x;
            lw[(il + 1) * 260 + row] = w4.y;
            lw[(il + 2) * 260 + row] = w4.z;
            lw[(il + 3) * 260 + row] = w4.w;
        }
        __syncthreads();
        unsigned sx[16];
        #pragma unroll
        for (int k = 0; k < 16; ++k)
            sx[k] = (unsigned)__builtin_amdgcn_readfirstlane(
                (int)xb32[(bb + k) * 128 + (i0 >> 5)]);
        #pragma unroll 4
        for (int ii = 0; ii < 32; ++ii) {
            float4 w4 = *(float4*)&lw[ii * 260 + 4 * lane];
            #pragma unroll
            for (int k = 0; k < 16; ++k) {
                if ((sx[k] >> ii) & 1u) {
                    acc[k].x += w4.x; acc[k].y += w4.y;
                    acc[k].z += w4.z; acc[k].w += w4.w;
                }
            }
        }
    }
    #pragma unroll
    for (int k = 0; k < 16; ++k) {
        *(float4*)&C[(size_t)blockIdx.y * (BATCH * HID) + (size_t)(bb + k) * HID +
                     hb + 4 * lane] = acc[k];
    }
}

// ---------------- K1b: in-place exclusive prefix -> P = -(c+prefix)*log2e ----------------
__global__ __launch_bounds__(256) void k_prefix(const float* __restrict__ cvec,
                                                float* __restrict__ CP) {
    int idx = blockIdx.x * 256 + threadIdx.x;   // = b*2048 + h, 0..131071
    int h = idx & (HID - 1);
    float run = cvec[h];
    #pragma unroll 4
    for (int s = 0; s < NSEG; ++s) {
        size_t o = (size_t)s * (BATCH * HID) + idx;
        float cs = CP[o];           // read segment sum first (aliased buffer)
        CP[o] = -LOG2E * run;       // write P[s]
        run += cs;
    }
}

// ---------------- K2: main scan ----------------
__global__ __launch_bounds__(256) void k_main(const float* __restrict__ W,
                                              const float* __restrict__ V,
                                              const unsigned* __restrict__ xb32,
                                              const float* __restrict__ P,
                                              float* __restrict__ WP) {
    __shared__ float lw[32 * 260];
    const int tid = threadIdx.x;
    const int lane = tid & 63;
    const int wv = tid >> 6;
    const int hb = blockIdx.x * 256;                 // 8 h-groups
    const int bb = blockIdx.y * 16 + wv * 4;         // 4 b-supergroups, 4 b per wave
    const int ib = blockIdx.z * ISEG;                // 32 segments
    const int hh = hb + 4 * lane;

    float4 n[4], s[4];
    #pragma unroll
    for (int k = 0; k < 4; ++k) {
        n[k] = *(const float4*)&P[(size_t)blockIdx.z * (BATCH * HID) +
                                  (size_t)(bb + k) * HID + hh];
        s[k].x = sig_from_n(n[k].x); s[k].y = sig_from_n(n[k].y);
        s[k].z = sig_from_n(n[k].z); s[k].w = sig_from_n(n[k].w);
    }

    for (int t = 0; t < 4; ++t) {
        const int i0 = ib + t * 32;
        __syncthreads();
        #pragma unroll
        for (int rep = 0; rep < 8; ++rep) {
            int idx = rep * 256 + tid;
            int row = idx >> 3, q = idx & 7;
            float4 w4 = *(const float4*)&W[(size_t)(hb + row) * NN + i0 + q * 4];
            int il = q * 4;
            lw[(il + 0) * 260 + row] = w4.x * LOG2E;
            lw[(il + 1) * 260 + row] = w4.y * LOG2E;
            lw[(il + 2) * 260 + row] = w4.z * LOG2E;
            lw[(il + 3) * 260 + row] = w4.w * LOG2E;
        }
        __syncthreads();
        unsigned sx[4];
        #pragma unroll
        for (int k = 0; k < 4; ++k)
            sx[k] = (unsigned)__builtin_amdgcn_readfirstlane(
                (int)xb32[(bb + k) * 128 + (i0 >> 5)]);
        #pragma unroll 4
        for (int ii = 0; ii < 32; ++ii) {
            const int ig = i0 + ii;
            float4 w4 = *(float4*)&lw[ii * 260 + 4 * lane];
            float4 v4 = *(const float4*)&V[(size_t)ig * HID + hh];
            float p[4];
            #pragma unroll
            for (int k = 0; k < 4; ++k)
                p[k] = s[k].x * v4.x + s[k].y * v4.y + s[k].z * v4.z + s[k].w * v4.w;
            #pragma unroll
            for (int k = 0; k < 4; ++k) {
                p[k] += __shfl_xor(p[k], 32);
                p[k] += __shfl_xor(p[k], 16);
                p[k] += __shfl_xor(p[k], 8);
                p[k] += __shfl_xor(p[k], 4);
                p[k] += __shfl_xor(p[k], 2);
                p[k] += __shfl_xor(p[k], 1);
            }
            if (lane < 4) {
                float pv = lane == 0 ? p[0] : lane == 1 ? p[1] : lane == 2 ? p[2] : p[3];
                WP[((size_t)(bb + lane) * NN + ig) * 8 + blockIdx.x] = pv;
            }
            #pragma unroll
            for (int k = 0; k < 4; ++k) {
                if ((sx[k] >> ii) & 1u) {
                    n[k].x -= w4.x; n[k].y -= w4.y; n[k].z -= w4.z; n[k].w -= w4.w;
                    s[k].x = sig_from_n(n[k].x); s[k].y = sig_from_n(n[k].y);
                    s[k].z = sig_from_n(n[k].z); s[k].w = sig_from_n(n[k].w);
                }
            }
        }
    }
}

// ---------------- K3: finalize ----------------
__global__ __launch_bounds__(256) void k_final(const float* __restrict__ WP,
                                               const float* __restrict__ x,
                                               const float* __restrict__ bv,
                                               float* __restrict__ out) {
    const int b = blockIdx.x, tid = threadIdx.x;
    float acc = 0.f;
    for (int i = tid; i < NN; i += 256) {
        const float4* pp = (const float4*)&WP[((size_t)b * NN + i) * 8];
        float4 a0 = pp[0], a1 = pp[1];
        float l = bv[i] + a0.x + a0.y + a0.z + a0.w + a1.x + a1.y + a1.z + a1.w;
        float xi = x[(size_t)b * NN + i];
        float al = fabsf(l);
        float e = __builtin_amdgcn_exp2f(-al * LOG2E);
        float lp = __logf(1.0f + e);
        acc += fminf(l, 0.0f) - lp - (1.0f - xi) * l;
    }
    __shared__ float red[256];
    red[tid] = acc;
    __syncthreads();
    for (int sft = 128; sft > 0; sft >>= 1) {
        if (tid < sft) red[tid] += red[tid + sft];
        __syncthreads();
    }
    if (tid == 0) out[b] = red[0];
}

extern "C" void kernel_launch(void* const* d_in, const int* in_sizes, int n_in,
                              void* d_out, int out_size, void* d_ws, size_t ws_size,
                              hipStream_t stream) {
    const float* x  = (const float*)d_in[0];
    const float* W  = (const float*)d_in[1];
    const float* c  = (const float*)d_in[2];
    const float* V  = (const float*)d_in[3];
    const float* bv = (const float*)d_in[4];
    float* out = (float*)d_out;

    char* ws = (char*)d_ws;
    unsigned long long* xbits = (unsigned long long*)ws;              // 32 KB
    float* CP = (float*)(ws + (1 << 16));                             // 16 MB (C, then P in-place)
    float* WP = (float*)(ws + (1 << 16) + (size_t)NSEG * BATCH * HID * 4); // 8 MB

    k_pack<<<dim3(1024), dim3(256), 0, stream>>>(x, xbits);
    k_partial<<<dim3(8, NSEG), dim3(256), 0, stream>>>(W, (const unsigned*)xbits, CP);
    k_prefix<<<dim3(512), dim3(256), 0, stream>>>(c, CP);
    k_main<<<dim3(8, 4, NSEG), dim3(256), 0, stream>>>(W, V, (const unsigned*)xbits, CP, WP);
    k_final<<<dim3(64), dim3(256), 0, stream>>>(WP, x, bv, out);
}

// Round 2
// 199.308 us; speedup vs baseline: 1.4825x; 1.4825x over previous
//
#include <hip/hip_runtime.h>
#include <hip/hip_bf16.h>

#define NN 4096
#define HID 2048
#define BATCH 64
#define NSEG 32
#define ISEG 128          // 4096/32
#define LPAD 261          // 261 % 32 = 5 -> staging writes hit distinct banks
#define LOG2E 1.4426950408889634f

__device__ __forceinline__ float rcpf(float v) { return __builtin_amdgcn_rcpf(v); }
__device__ __forceinline__ float exp2f_(float v) { return __builtin_amdgcn_exp2f(v); }

template <int CTRL>
__device__ __forceinline__ float ror_add(float x) {
    int t = __builtin_amdgcn_update_dpp(0, __builtin_bit_cast(int, x), CTRL, 0xF, 0xF, true);
    return x + __builtin_bit_cast(float, t);
}

// ---------------- K0: pack x bits ----------------
__global__ __launch_bounds__(256) void k_pack(const float* __restrict__ x,
                                              unsigned long long* __restrict__ xbits) {
    int gw = blockIdx.x * 4 + (threadIdx.x >> 6);   // global wave id, 0..4095
    int lane = threadIdx.x & 63;
    int b = gw >> 6, w = gw & 63;
    float v = x[(size_t)b * NN + w * 64 + lane];
    unsigned long long m = __ballot(v > 0.5f);
    if (lane == 0) xbits[b * 64 + w] = m;
}

// ---------------- K1: per-segment sums C[seg][b][h] (8 batches per wave) --------
__global__ __launch_bounds__(256) void k_partial(const float* __restrict__ W,
                                                 const unsigned* __restrict__ xb32,
                                                 float* __restrict__ C) {
    __shared__ float lw[32 * LPAD];
    const int tid = threadIdx.x;
    const int lane = tid & 63;
    const int wv = tid >> 6;
    const int hb = blockIdx.x * 256;
    const int ib = blockIdx.y * ISEG;
    const int bb = blockIdx.z * 32 + wv * 8;

    float4 acc[8];
    #pragma unroll
    for (int k = 0; k < 8; ++k) acc[k] = make_float4(0.f, 0.f, 0.f, 0.f);

    for (int t = 0; t < 4; ++t) {
        const int i0 = ib + t * 32;
        __syncthreads();
        #pragma unroll
        for (int rep = 0; rep < 8; ++rep) {
            int idx = rep * 256 + tid;
            int row = idx >> 3, q = idx & 7;
            float4 w4 = *(const float4*)&W[(size_t)(hb + row) * NN + i0 + q * 4];
            int il = q * 4;
            lw[(il + 0) * LPAD + row] = w4.x;
            lw[(il + 1) * LPAD + row] = w4.y;
            lw[(il + 2) * LPAD + row] = w4.z;
            lw[(il + 3) * LPAD + row] = w4.w;
        }
        __syncthreads();
        unsigned sx[8];
        #pragma unroll
        for (int k = 0; k < 8; ++k)
            sx[k] = (unsigned)__builtin_amdgcn_readfirstlane(
                (int)xb32[(bb + k) * 128 + (i0 >> 5)]);
        #pragma unroll 4
        for (int ii = 0; ii < 32; ++ii) {
            float4 w4 = *(float4*)&lw[ii * LPAD + 4 * lane];
            #pragma unroll
            for (int k = 0; k < 8; ++k) {
                if ((sx[k] >> ii) & 1u) {
                    acc[k].x += w4.x; acc[k].y += w4.y;
                    acc[k].z += w4.z; acc[k].w += w4.w;
                }
            }
        }
    }
    #pragma unroll
    for (int k = 0; k < 8; ++k) {
        *(float4*)&C[(size_t)blockIdx.y * (BATCH * HID) + (size_t)(bb + k) * HID +
                     hb + 4 * lane] = acc[k];
    }
}

// ---------------- K1b: in-place exclusive prefix -> P = -(c+prefix)*log2e -------
__global__ __launch_bounds__(256) void k_prefix(const float* __restrict__ cvec,
                                                float* __restrict__ CP) {
    int idx = blockIdx.x * 256 + threadIdx.x;   // = b*2048 + h
    int h = idx & (HID - 1);
    float run = cvec[h];
    #pragma unroll 4
    for (int s = 0; s < NSEG; ++s) {
        size_t o = (size_t)s * (BATCH * HID) + idx;
        float cs = CP[o];           // read segment sum first (aliased buffer)
        CP[o] = -LOG2E * run;       // write P[s]
        run += cs;
    }
}

// ---------------- K2: main scan ----------------
__global__ __launch_bounds__(256) void k_main(const float* __restrict__ W,
                                              const float* __restrict__ V,
                                              const unsigned* __restrict__ xb32,
                                              const float* __restrict__ P,
                                              float* __restrict__ WP) {
    __shared__ float lw[32 * LPAD];
    const int tid = threadIdx.x;
    const int lane = tid & 63;
    const int wv = tid >> 6;
    const int hb = blockIdx.x * 256;                 // 8 h-groups
    const int bb = blockIdx.y * 16 + wv * 4;         // 4 b per wave
    const int ib = blockIdx.z * ISEG;                // 32 segments
    const int hh = hb + 4 * lane;

    const bool hi16 = (lane & 16) != 0;
    const bool hi32 = (lane & 32) != 0;

    // state: u = 2^(-(c+a)*log2e), sigmoid s = 1/(1+u)
    float4 u[4], s[4];
    #pragma unroll
    for (int k = 0; k < 4; ++k) {
        float4 nk = *(const float4*)&P[(size_t)blockIdx.z * (BATCH * HID) +
                                       (size_t)(bb + k) * HID + hh];
        u[k].x = exp2f_(nk.x); u[k].y = exp2f_(nk.y);
        u[k].z = exp2f_(nk.z); u[k].w = exp2f_(nk.w);
        s[k].x = rcpf(1.0f + u[k].x); s[k].y = rcpf(1.0f + u[k].y);
        s[k].z = rcpf(1.0f + u[k].z); s[k].w = rcpf(1.0f + u[k].w);
    }

    for (int t = 0; t < 4; ++t) {
        const int i0 = ib + t * 32;
        __syncthreads();
        #pragma unroll
        for (int rep = 0; rep < 8; ++rep) {
            int idx = rep * 256 + tid;
            int row = idx >> 3, q = idx & 7;
            float4 w4 = *(const float4*)&W[(size_t)(hb + row) * NN + i0 + q * 4];
            int il = q * 4;
            // stage uw = 2^(-w * log2e): state update is u *= uw
            lw[(il + 0) * LPAD + row] = exp2f_(-LOG2E * w4.x);
            lw[(il + 1) * LPAD + row] = exp2f_(-LOG2E * w4.y);
            lw[(il + 2) * LPAD + row] = exp2f_(-LOG2E * w4.z);
            lw[(il + 3) * LPAD + row] = exp2f_(-LOG2E * w4.w);
        }
        __syncthreads();
        unsigned sx[4];
        #pragma unroll
        for (int k = 0; k < 4; ++k)
            sx[k] = (unsigned)__builtin_amdgcn_readfirstlane(
                (int)xb32[(bb + k) * 128 + (i0 >> 5)]);
        #pragma unroll 4
        for (int ii = 0; ii < 32; ++ii) {
            const int ig = i0 + ii;
            float4 w4 = *(float4*)&lw[ii * LPAD + 4 * lane];
            float4 v4 = *(const float4*)&V[(size_t)ig * HID + hh];
            float p[4];
            #pragma unroll
            for (int k = 0; k < 4; ++k)
                p[k] = s[k].x * v4.x + s[k].y * v4.y + s[k].z * v4.z + s[k].w * v4.w;

            // fold 4 independent 64-lane sums into one value per 16-lane group
            float a01k = hi16 ? p[1] : p[0];
            float a01s = hi16 ? p[0] : p[1];
            float y01 = a01k + __shfl_xor(a01s, 16);
            float a23k = hi16 ? p[3] : p[2];
            float a23s = hi16 ? p[2] : p[3];
            float y23 = a23k + __shfl_xor(a23s, 16);
            float bk = hi32 ? y23 : y01;
            float bs = hi32 ? y01 : y23;
            float z = bk + __shfl_xor(bs, 32);
            // reduce within 16-lane group: DPP row rotations, pure VALU
            z = ror_add<0x128>(z);
            z = ror_add<0x124>(z);
            z = ror_add<0x122>(z);
            z = ror_add<0x121>(z);
            if ((lane & 15) == 0) {
                WP[((size_t)(blockIdx.x * BATCH + bb + (lane >> 4))) * NN + ig] = z;
            }
            #pragma unroll
            for (int k = 0; k < 4; ++k) {
                if ((sx[k] >> ii) & 1u) {
                    u[k].x *= w4.x; u[k].y *= w4.y; u[k].z *= w4.z; u[k].w *= w4.w;
                    s[k].x = rcpf(1.0f + u[k].x); s[k].y = rcpf(1.0f + u[k].y);
                    s[k].z = rcpf(1.0f + u[k].z); s[k].w = rcpf(1.0f + u[k].w);
                }
            }
        }
    }
}

// ---------------- K3: finalize ----------------
__global__ __launch_bounds__(256) void k_final(const float* __restrict__ WP,
                                               const float* __restrict__ x,
                                               const float* __restrict__ bv,
                                               float* __restrict__ out) {
    const int b = blockIdx.x, tid = threadIdx.x;
    float acc = 0.f;
    for (int i = tid; i < NN; i += 256) {
        float l = bv[i];
        #pragma unroll
        for (int j = 0; j < 8; ++j)
            l += WP[((size_t)(j * BATCH + b)) * NN + i];
        float xi = x[(size_t)b * NN + i];
        float al = fabsf(l);
        float e = exp2f_(-al * LOG2E);
        float lp = __logf(1.0f + e);
        acc += fminf(l, 0.0f) - lp - (1.0f - xi) * l;
    }
    __shared__ float red[256];
    red[tid] = acc;
    __syncthreads();
    for (int sft = 128; sft > 0; sft >>= 1) {
        if (tid < sft) red[tid] += red[tid + sft];
        __syncthreads();
    }
    if (tid == 0) out[b] = red[0];
}

extern "C" void kernel_launch(void* const* d_in, const int* in_sizes, int n_in,
                              void* d_out, int out_size, void* d_ws, size_t ws_size,
                              hipStream_t stream) {
    const float* x  = (const float*)d_in[0];
    const float* W  = (const float*)d_in[1];
    const float* c  = (const float*)d_in[2];
    const float* V  = (const float*)d_in[3];
    const float* bv = (const float*)d_in[4];
    float* out = (float*)d_out;

    char* ws = (char*)d_ws;
    unsigned long long* xbits = (unsigned long long*)ws;              // 32 KB
    float* CP = (float*)(ws + (1 << 16));                             // 16 MB (C, then P in-place)
    float* WP = (float*)(ws + (1 << 16) + (size_t)NSEG * BATCH * HID * 4); // 8 MB

    k_pack<<<dim3(1024), dim3(256), 0, stream>>>(x, xbits);
    k_partial<<<dim3(8, NSEG, 2), dim3(256), 0, stream>>>(W, (const unsigned*)xbits, CP);
    k_prefix<<<dim3(512), dim3(256), 0, stream>>>(c, CP);
    k_main<<<dim3(8, 4, NSEG), dim3(256), 0, stream>>>(W, V, (const unsigned*)xbits, CP, WP);
    k_final<<<dim3(64), dim3(256), 0, stream>>>(WP, x, bv, out);
}